// Round 3
// baseline (635.167 us; speedup 1.0000x reference)
//
#include <hip/hip_runtime.h>
#include <stdint.h>

typedef unsigned short u16;

#define E_    8
#define DIM_  1024
#define HID_  2048
#define H2_   4096     // 2*HID
#define NTOK  8192     // B*T

typedef __attribute__((ext_vector_type(8))) short bf16x8;
typedef __attribute__((ext_vector_type(4))) float f32x4;

__device__ __forceinline__ u16 f2bf(float f) {
  uint32_t u = __builtin_bit_cast(uint32_t, f);
  uint32_t r = (u + 0x7FFFu + ((u >> 16) & 1u)) >> 16;
  return (u16)r;
}

__device__ __forceinline__ void gload16(const void* g, void* l) {
  __builtin_amdgcn_global_load_lds(
      (const __attribute__((address_space(1))) void*)g,
      (__attribute__((address_space(3))) void*)l, 16, 0, 0);
}

// ---------------- conversion kernels ----------------

__global__ void cvt_x(const float* __restrict__ x, u16* __restrict__ xb, int n8) {
  int i = blockIdx.x * blockDim.x + threadIdx.x;
  if (i >= n8) return;
  const float4* p = (const float4*)(x + (size_t)i * 8);
  float4 a = p[0], b = p[1];
  union { u16 u[8]; uint4 v; } r;
  r.u[0] = f2bf(a.x); r.u[1] = f2bf(a.y); r.u[2] = f2bf(a.z); r.u[3] = f2bf(a.w);
  r.u[4] = f2bf(b.x); r.u[5] = f2bf(b.y); r.u[6] = f2bf(b.z); r.u[7] = f2bf(b.w);
  *(uint4*)(xb + (size_t)i * 8) = r.v;
}

// src [e][R][C] fp32 -> dst [e][C][R] bf16 (32x32 tiles)
__global__ void tconv(const float* __restrict__ src, u16* __restrict__ dst, int R, int C) {
  __shared__ float t[32][33];
  int e = blockIdx.z;
  int r0 = blockIdx.y * 32, c0 = blockIdx.x * 32;
  const float* s = src + (size_t)e * R * C;
  u16* d = dst + (size_t)e * R * C;
  int tid = threadIdx.x;
  int rr = tid >> 3, cc = (tid & 7) * 4;
  float4 v = *(const float4*)(s + (size_t)(r0 + rr) * C + c0 + cc);
  t[rr][cc + 0] = v.x; t[rr][cc + 1] = v.y; t[rr][cc + 2] = v.z; t[rr][cc + 3] = v.w;
  __syncthreads();
  ushort4 w;
  w.x = f2bf(t[cc + 0][rr]);
  w.y = f2bf(t[cc + 1][rr]);
  w.z = f2bf(t[cc + 2][rr]);
  w.w = f2bf(t[cc + 3][rr]);
  *(ushort4*)(d + (size_t)(c0 + rr) * R + r0 + cc) = w;
}

// ---------------- router ----------------

__global__ void router(const float* __restrict__ x, const float* __restrict__ rw,
                       const float* __restrict__ rb, int* __restrict__ counts,
                       int* __restrict__ btok, float* __restrict__ bw) {
  int wid = threadIdx.x >> 6, lane = threadIdx.x & 63;
  int t = blockIdx.x * 4 + wid;
  const float* xt = x + (size_t)t * DIM_;
  float acc[8] = {0.f, 0.f, 0.f, 0.f, 0.f, 0.f, 0.f, 0.f};
#pragma unroll
  for (int it = 0; it < 4; ++it) {
    int d = it * 256 + lane * 4;
    float4 xv = *(const float4*)(xt + d);
#pragma unroll
    for (int e = 0; e < 8; ++e) {
      float4 rv = *(const float4*)(rw + e * DIM_ + d);
      acc[e] += xv.x * rv.x + xv.y * rv.y + xv.z * rv.z + xv.w * rv.w;
    }
  }
#pragma unroll
  for (int e = 0; e < 8; ++e)
#pragma unroll
    for (int off = 32; off; off >>= 1)
      acc[e] += __shfl_xor(acc[e], off, 64);
  if (lane == 0) {
    float v[8];
#pragma unroll
    for (int e = 0; e < 8; ++e) v[e] = acc[e] + rb[e];
    int i0 = 0;
#pragma unroll
    for (int e = 1; e < 8; ++e) if (v[e] > v[i0]) i0 = e;
    int i1 = (i0 == 0) ? 1 : 0;
#pragma unroll
    for (int e = 0; e < 8; ++e) if (e != i0 && v[e] > v[i1]) i1 = e;
    float w0 = 1.f / (1.f + expf(v[i1] - v[i0]));
    float w1 = 1.f - w0;
    int p0 = atomicAdd(&counts[i0], 1);
    btok[i0 * NTOK + p0] = t; bw[i0 * NTOK + p0] = w0;
    int p1 = atomicAdd(&counts[i1], 1);
    btok[i1 * NTOK + p1] = t; bw[i1 * NTOK + p1] = w1;
  }
}

// ---------------- GEMM1: gathered x @ W1 -> swiglu -> hb ----------------
// block tile: 128 rows x 128 B-cols (= 64 swiglu output cols), BK=64
// B-tile row r -> W1 col: nblk*64 + (r>>6)*32 + (r&31) + ((r>>5)&1)*2048

__launch_bounds__(256, 2)
__global__ void gemm1(const u16* __restrict__ xb, const u16* __restrict__ w1t,
                      const float* __restrict__ b1, const int* __restrict__ counts,
                      const int* __restrict__ btok, u16* __restrict__ hb) {
  int e = blockIdx.z, mblk = blockIdx.y, nblk = blockIdx.x;
  int cnt = counts[e];
  if (mblk * 128 >= cnt) return;
  int base = 0;
#pragma unroll
  for (int i = 0; i < 8; ++i) base += (i < e) ? counts[i] : 0;

  __shared__ u16 lA[128 * 64];
  __shared__ u16 lB[128 * 64];
  __shared__ int sTok[128];

  int tid = threadIdx.x, wid = tid >> 6, lane = tid & 63;
  if (tid < 128) {
    int gr = mblk * 128 + tid;
    sTok[tid] = (gr < cnt) ? btok[e * NTOK + gr] : btok[e * NTOK];
  }
  __syncthreads();

  f32x4 acc[4][4] = {};
  int wr = wid >> 1, wc = wid & 1;
  int l15 = lane & 15, lhi = lane >> 4;
  const size_t w1e = (size_t)e * H2_ * DIM_;

  for (int kt = 0; kt < DIM_ / 64; ++kt) {
#pragma unroll
    for (int i = 0; i < 4; ++i) {
      int r = wid * 32 + i * 8 + (lane >> 3);
      const u16* g = xb + (size_t)sTok[r] * DIM_ + kt * 64 + (lane & 7) * 8;
      gload16(g, &lA[(wid * 32 + i * 8) * 64]);
    }
#pragma unroll
    for (int i = 0; i < 4; ++i) {
      int r = wid * 32 + i * 8 + (lane >> 3);
      int gcol = nblk * 64 + (r >> 6) * 32 + (r & 31) + ((r >> 5) & 1) * 2048;
      const u16* g = w1t + w1e + (size_t)gcol * DIM_ + kt * 64 + (lane & 7) * 8;
      gload16(g, &lB[(wid * 32 + i * 8) * 64]);
    }
    __syncthreads();
#pragma unroll
    for (int ks = 0; ks < 2; ++ks) {
      bf16x8 a[4], b[4];
#pragma unroll
      for (int m = 0; m < 4; ++m)
        a[m] = *(const bf16x8*)&lA[(wr * 64 + m * 16 + l15) * 64 + ks * 32 + lhi * 8];
#pragma unroll
      for (int n = 0; n < 4; ++n)
        b[n] = *(const bf16x8*)&lB[(wc * 64 + n * 16 + l15) * 64 + ks * 32 + lhi * 8];
#pragma unroll
      for (int m = 0; m < 4; ++m)
#pragma unroll
        for (int n = 0; n < 4; ++n)
          acc[m][n] = __builtin_amdgcn_mfma_f32_16x16x32_bf16(a[m], b[n], acc[m][n], 0, 0, 0);
    }
    __syncthreads();
  }

  // epilogue: swiglu( h1 = frag n, h2 = frag n+2 ) -> hb
#pragma unroll
  for (int n = 0; n < 2; ++n) {
    int outcol = nblk * 64 + wc * 32 + n * 16 + l15;   // in [0,2048)
    float bb1 = b1[e * H2_ + outcol];
    float bb2 = b1[e * H2_ + outcol + HID_];
#pragma unroll
    for (int m = 0; m < 4; ++m) {
#pragma unroll
      for (int j = 0; j < 4; ++j) {
        int rt = wr * 64 + m * 16 + lhi * 4 + j;
        int gr = mblk * 128 + rt;
        if (gr < cnt) {
          float h1 = acc[m][n][j] + bb1;
          float h2 = acc[m][n + 2][j] + bb2;
          float s = (h1 / (1.f + __expf(-h1))) * h2;
          hb[(size_t)(base + gr) * HID_ + outcol] = f2bf(s);
        }
      }
    }
  }
}

// ---------------- GEMM2: hb @ W2 -> weighted scatter-add to out ----------------

__launch_bounds__(256, 2)
__global__ void gemm2(const u16* __restrict__ hb, const u16* __restrict__ w2t,
                      const float* __restrict__ b2, const int* __restrict__ counts,
                      const int* __restrict__ btok, const float* __restrict__ bw,
                      float* __restrict__ out) {
  int e = blockIdx.z, mblk = blockIdx.y, nblk = blockIdx.x;
  int cnt = counts[e];
  if (mblk * 128 >= cnt) return;
  int base = 0;
#pragma unroll
  for (int i = 0; i < 8; ++i) base += (i < e) ? counts[i] : 0;

  __shared__ u16 lA[128 * 64];
  __shared__ u16 lB[128 * 64];
  __shared__ int sTok[128];
  __shared__ float sW[128];

  int tid = threadIdx.x, wid = tid >> 6, lane = tid & 63;
  if (tid < 128) {
    int gr = mblk * 128 + tid;
    bool v = gr < cnt;
    sTok[tid] = v ? btok[e * NTOK + gr] : 0;
    sW[tid]   = v ? bw[e * NTOK + gr] : 0.f;
  }
  __syncthreads();

  f32x4 acc[4][4] = {};
  int wr = wid >> 1, wc = wid & 1;
  int l15 = lane & 15, lhi = lane >> 4;
  const u16* Abase = hb + (size_t)(base + mblk * 128) * HID_;
  const u16* Bbase = w2t + (size_t)e * DIM_ * HID_ + (size_t)(nblk * 128) * HID_;

  for (int kt = 0; kt < HID_ / 64; ++kt) {
#pragma unroll
    for (int i = 0; i < 4; ++i) {
      int r = wid * 32 + i * 8 + (lane >> 3);
      gload16(Abase + (size_t)r * HID_ + kt * 64 + (lane & 7) * 8, &lA[(wid * 32 + i * 8) * 64]);
      gload16(Bbase + (size_t)r * HID_ + kt * 64 + (lane & 7) * 8, &lB[(wid * 32 + i * 8) * 64]);
    }
    __syncthreads();
#pragma unroll
    for (int ks = 0; ks < 2; ++ks) {
      bf16x8 a[4], b[4];
#pragma unroll
      for (int m = 0; m < 4; ++m)
        a[m] = *(const bf16x8*)&lA[(wr * 64 + m * 16 + l15) * 64 + ks * 32 + lhi * 8];
#pragma unroll
      for (int n = 0; n < 4; ++n)
        b[n] = *(const bf16x8*)&lB[(wc * 64 + n * 16 + l15) * 64 + ks * 32 + lhi * 8];
#pragma unroll
      for (int m = 0; m < 4; ++m)
#pragma unroll
        for (int n = 0; n < 4; ++n)
          acc[m][n] = __builtin_amdgcn_mfma_f32_16x16x32_bf16(a[m], b[n], acc[m][n], 0, 0, 0);
    }
    __syncthreads();
  }

#pragma unroll
  for (int n = 0; n < 4; ++n) {
    int col = nblk * 128 + wc * 64 + n * 16 + l15;
    float bb = b2[e * DIM_ + col];
#pragma unroll
    for (int m = 0; m < 4; ++m) {
#pragma unroll
      for (int j = 0; j < 4; ++j) {
        int rt = wr * 64 + m * 16 + lhi * 4 + j;
        int gr = mblk * 128 + rt;
        if (gr < cnt)
          atomicAdd(out + (size_t)sTok[rt] * DIM_ + col, sW[rt] * (acc[m][n][j] + bb));
      }
    }
  }
}

// ---------------- launch ----------------

extern "C" void kernel_launch(void* const* d_in, const int* in_sizes, int n_in,
                              void* d_out, int out_size, void* d_ws, size_t ws_size,
                              hipStream_t stream) {
  const float* x  = (const float*)d_in[0];
  const float* rw = (const float*)d_in[1];
  const float* rb = (const float*)d_in[2];
  const float* W1 = (const float*)d_in[3];
  const float* b1 = (const float*)d_in[4];
  const float* W2 = (const float*)d_in[5];
  const float* b2 = (const float*)d_in[6];
  float* out = (float*)d_out;

  char* ws = (char*)d_ws;
  int*   counts = (int*)ws;                       // 32 B
  int*   btok   = (int*)(ws + 256);               // 8*8192*4 = 256 KB
  float* bw     = (float*)(ws + 256 + 262144);    // 256 KB
  u16* xb  = (u16*)(ws + (1u << 20));             // 16 MB
  u16* w1t = xb  + (size_t)NTOK * DIM_;           // 64 MB
  u16* w2t = w1t + (size_t)E_ * H2_ * DIM_;       // 32 MB
  u16* hb  = w2t + (size_t)E_ * DIM_ * HID_;      // (16384+128)*2048*2 B

  hipMemsetAsync(out, 0, (size_t)out_size * sizeof(float), stream);
  hipMemsetAsync(counts, 0, 8 * sizeof(int), stream);

  cvt_x<<<(NTOK * DIM_ / 8 + 255) / 256, 256, 0, stream>>>(x, xb, NTOK * DIM_ / 8);
  tconv<<<dim3(H2_ / 32, DIM_ / 32, E_), 256, 0, stream>>>(W1, w1t, DIM_, H2_);
  tconv<<<dim3(DIM_ / 32, HID_ / 32, E_), 256, 0, stream>>>(W2, w2t, HID_, DIM_);
  router<<<NTOK / 4, 256, 0, stream>>>(x, rw, rb, counts, btok, bw);

  gemm1<<<dim3(H2_ / 128, NTOK / 128, E_), 256, 0, stream>>>(xb, w1t, b1, counts, btok, hb);
  gemm2<<<dim3(DIM_ / 128, NTOK / 128, E_), 256, 0, stream>>>(hb, w2t, b2, counts, btok, bw, out);
}

// Round 4
// 568.702 us; speedup vs baseline: 1.1169x; 1.1169x over previous
//
#include <hip/hip_runtime.h>
#include <stdint.h>

typedef unsigned short u16;

#define E_    8
#define DIM_  1024
#define HID_  2048
#define H2_   4096     // 2*HID
#define NTOK  8192     // B*T

typedef __attribute__((ext_vector_type(8))) short bf16x8;
typedef __attribute__((ext_vector_type(4))) float f32x4;

__device__ __forceinline__ u16 f2bf(float f) {
  uint32_t u = __builtin_bit_cast(uint32_t, f);
  uint32_t r = (u + 0x7FFFu + ((u >> 16) & 1u)) >> 16;
  return (u16)r;
}
__device__ __forceinline__ float bf2f(u16 u) {
  return __builtin_bit_cast(float, (uint32_t)u << 16);
}

__device__ __forceinline__ void gload16(const void* g, void* l) {
  __builtin_amdgcn_global_load_lds(
      (const __attribute__((address_space(1))) void*)g,
      (__attribute__((address_space(3))) void*)l, 16, 0, 0);
}

// ---------------- conversion kernels ----------------

__global__ void cvt_x(const float* __restrict__ x, u16* __restrict__ xb, int n8) {
  int i = blockIdx.x * blockDim.x + threadIdx.x;
  if (i >= n8) return;
  const float4* p = (const float4*)(x + (size_t)i * 8);
  float4 a = p[0], b = p[1];
  union { u16 u[8]; uint4 v; } r;
  r.u[0] = f2bf(a.x); r.u[1] = f2bf(a.y); r.u[2] = f2bf(a.z); r.u[3] = f2bf(a.w);
  r.u[4] = f2bf(b.x); r.u[5] = f2bf(b.y); r.u[6] = f2bf(b.z); r.u[7] = f2bf(b.w);
  *(uint4*)(xb + (size_t)i * 8) = r.v;
}

// src [e][R][C] fp32 -> dst [e][C][R] bf16 (32x32 tiles)
__global__ void tconv(const float* __restrict__ src, u16* __restrict__ dst, int R, int C) {
  __shared__ float t[32][33];
  int e = blockIdx.z;
  int r0 = blockIdx.y * 32, c0 = blockIdx.x * 32;
  const float* s = src + (size_t)e * R * C;
  u16* d = dst + (size_t)e * R * C;
  int tid = threadIdx.x;
  int rr = tid >> 3, cc = (tid & 7) * 4;
  float4 v = *(const float4*)(s + (size_t)(r0 + rr) * C + c0 + cc);
  t[rr][cc + 0] = v.x; t[rr][cc + 1] = v.y; t[rr][cc + 2] = v.z; t[rr][cc + 3] = v.w;
  __syncthreads();
  ushort4 w;
  w.x = f2bf(t[cc + 0][rr]);
  w.y = f2bf(t[cc + 1][rr]);
  w.z = f2bf(t[cc + 2][rr]);
  w.w = f2bf(t[cc + 3][rr]);
  *(ushort4*)(d + (size_t)(c0 + rr) * R + r0 + cc) = w;
}

// ---------------- router ----------------

__global__ void router(const float* __restrict__ x, const float* __restrict__ rw,
                       const float* __restrict__ rb, int* __restrict__ counts,
                       int* __restrict__ btok, float* __restrict__ bw,
                       int* __restrict__ tokrec) {
  int wid = threadIdx.x >> 6, lane = threadIdx.x & 63;
  int t = blockIdx.x * 4 + wid;
  const float* xt = x + (size_t)t * DIM_;
  float acc[8] = {0.f, 0.f, 0.f, 0.f, 0.f, 0.f, 0.f, 0.f};
#pragma unroll
  for (int it = 0; it < 4; ++it) {
    int d = it * 256 + lane * 4;
    float4 xv = *(const float4*)(xt + d);
#pragma unroll
    for (int e = 0; e < 8; ++e) {
      float4 rv = *(const float4*)(rw + e * DIM_ + d);
      acc[e] += xv.x * rv.x + xv.y * rv.y + xv.z * rv.z + xv.w * rv.w;
    }
  }
#pragma unroll
  for (int e = 0; e < 8; ++e)
#pragma unroll
    for (int off = 32; off; off >>= 1)
      acc[e] += __shfl_xor(acc[e], off, 64);
  if (lane == 0) {
    float v[8];
#pragma unroll
    for (int e = 0; e < 8; ++e) v[e] = acc[e] + rb[e];
    int i0 = 0;
#pragma unroll
    for (int e = 1; e < 8; ++e) if (v[e] > v[i0]) i0 = e;
    int i1 = (i0 == 0) ? 1 : 0;
#pragma unroll
    for (int e = 0; e < 8; ++e) if (e != i0 && v[e] > v[i1]) i1 = e;
    float w0 = 1.f / (1.f + expf(v[i1] - v[i0]));
    float w1 = 1.f - w0;
    int p0 = atomicAdd(&counts[i0], 1);
    btok[i0 * NTOK + p0] = t; bw[i0 * NTOK + p0] = w0;
    int p1 = atomicAdd(&counts[i1], 1);
    btok[i1 * NTOK + p1] = t; bw[i1 * NTOK + p1] = w1;
    tokrec[t * 2 + 0] = (i0 << 13) | p0;
    tokrec[t * 2 + 1] = (i1 << 13) | p1;
  }
}

// ---------------- GEMM1: gathered x @ W1 -> swiglu -> hb ----------------
// block tile: 128 rows x 128 B-cols (= 64 swiglu output cols), BK=64
// LDS tiles XOR-swizzled (T2): physical 16B segment s holds logical segment
// s ^ (row&7); staging pre-swizzles the GLOBAL source (rule #21), LDS dest
// stays linear for global_load_lds; reads apply the same XOR.

__launch_bounds__(256, 2)
__global__ void gemm1(const u16* __restrict__ xb, const u16* __restrict__ w1t,
                      const float* __restrict__ b1, const int* __restrict__ counts,
                      const int* __restrict__ btok, u16* __restrict__ hb) {
  int e = blockIdx.z, mblk = blockIdx.y, nblk = blockIdx.x;
  int cnt = counts[e];
  if (mblk * 128 >= cnt) return;
  int base = 0;
#pragma unroll
  for (int i = 0; i < 8; ++i) base += (i < e) ? counts[i] : 0;

  __shared__ u16 lA[128 * 64];
  __shared__ u16 lB[128 * 64];
  __shared__ int sTok[128];

  int tid = threadIdx.x, wid = tid >> 6, lane = tid & 63;
  if (tid < 128) {
    int gr = mblk * 128 + tid;
    sTok[tid] = (gr < cnt) ? btok[e * NTOK + gr] : btok[e * NTOK];
  }
  __syncthreads();

  f32x4 acc[4][4] = {};
  int wr = wid >> 1, wc = wid & 1;
  int l15 = lane & 15, lhi = lane >> 4;
  const size_t w1e = (size_t)e * H2_ * DIM_;

  // pre-swizzled source segment (u16 offset within the 64-elem row)
  int segsw = ((lane & 7) ^ ((lane >> 3) & 7)) * 8;
  const u16* gA[4];
  const u16* gB[4];
#pragma unroll
  for (int i = 0; i < 4; ++i) {
    int r = wid * 32 + i * 8 + (lane >> 3);
    gA[i] = xb + (size_t)sTok[r] * DIM_ + segsw;
    int gcol = nblk * 64 + (r >> 6) * 32 + (r & 31) + ((r >> 5) & 1) * 2048;
    gB[i] = w1t + w1e + (size_t)gcol * DIM_ + segsw;
  }
  int rxor = (l15 & 7) * 8;   // read-side swizzle term (u16 units)

  for (int kt = 0; kt < DIM_ / 64; ++kt) {
#pragma unroll
    for (int i = 0; i < 4; ++i)
      gload16(gA[i] + kt * 64, &lA[(wid * 32 + i * 8) * 64]);
#pragma unroll
    for (int i = 0; i < 4; ++i)
      gload16(gB[i] + kt * 64, &lB[(wid * 32 + i * 8) * 64]);
    __syncthreads();
#pragma unroll
    for (int ks = 0; ks < 2; ++ks) {
      int segrd = ((ks * 4 + lhi) * 8) ^ rxor;
      bf16x8 a[4], b[4];
#pragma unroll
      for (int m = 0; m < 4; ++m)
        a[m] = *(const bf16x8*)&lA[(wr * 64 + m * 16 + l15) * 64 + segrd];
#pragma unroll
      for (int n = 0; n < 4; ++n)
        b[n] = *(const bf16x8*)&lB[(wc * 64 + n * 16 + l15) * 64 + segrd];
#pragma unroll
      for (int m = 0; m < 4; ++m)
#pragma unroll
        for (int n = 0; n < 4; ++n)
          acc[m][n] = __builtin_amdgcn_mfma_f32_16x16x32_bf16(a[m], b[n], acc[m][n], 0, 0, 0);
    }
    __syncthreads();
  }

  // epilogue: swiglu( h1 = frag n, h2 = frag n+2 ) -> hb
#pragma unroll
  for (int n = 0; n < 2; ++n) {
    int outcol = nblk * 64 + wc * 32 + n * 16 + l15;   // in [0,2048)
    float bb1 = b1[e * H2_ + outcol];
    float bb2 = b1[e * H2_ + outcol + HID_];
#pragma unroll
    for (int m = 0; m < 4; ++m) {
#pragma unroll
      for (int j = 0; j < 4; ++j) {
        int rt = wr * 64 + m * 16 + lhi * 4 + j;
        int gr = mblk * 128 + rt;
        if (gr < cnt) {
          float h1 = acc[m][n][j] + bb1;
          float h2 = acc[m][n + 2][j] + bb2;
          float s = (h1 / (1.f + __expf(-h1))) * h2;
          hb[(size_t)(base + gr) * HID_ + outcol] = f2bf(s);
        }
      }
    }
  }
}

// ---------------- GEMM2: hb @ W2 -> w*(y+b2) stored bf16 to ybuf ----------------

__launch_bounds__(256, 2)
__global__ void gemm2(const u16* __restrict__ hb, const u16* __restrict__ w2t,
                      const float* __restrict__ b2, const int* __restrict__ counts,
                      const float* __restrict__ bw, u16* __restrict__ ybuf) {
  int e = blockIdx.z, mblk = blockIdx.y, nblk = blockIdx.x;
  int cnt = counts[e];
  if (mblk * 128 >= cnt) return;
  int base = 0;
#pragma unroll
  for (int i = 0; i < 8; ++i) base += (i < e) ? counts[i] : 0;

  __shared__ u16 lA[128 * 64];
  __shared__ u16 lB[128 * 64];
  __shared__ float sW[128];

  int tid = threadIdx.x, wid = tid >> 6, lane = tid & 63;
  if (tid < 128) {
    int gr = mblk * 128 + tid;
    sW[tid] = (gr < cnt) ? bw[e * NTOK + gr] : 0.f;
  }
  __syncthreads();

  f32x4 acc[4][4] = {};
  int wr = wid >> 1, wc = wid & 1;
  int l15 = lane & 15, lhi = lane >> 4;

  int segsw = ((lane & 7) ^ ((lane >> 3) & 7)) * 8;
  const u16* gA[4];
  const u16* gB[4];
#pragma unroll
  for (int i = 0; i < 4; ++i) {
    int r = wid * 32 + i * 8 + (lane >> 3);
    gA[i] = hb + (size_t)(base + mblk * 128 + r) * HID_ + segsw;
    gB[i] = w2t + (size_t)e * DIM_ * HID_ + (size_t)(nblk * 128 + r) * HID_ + segsw;
  }
  int rxor = (l15 & 7) * 8;

  for (int kt = 0; kt < HID_ / 64; ++kt) {
#pragma unroll
    for (int i = 0; i < 4; ++i) {
      gload16(gA[i] + kt * 64, &lA[(wid * 32 + i * 8) * 64]);
      gload16(gB[i] + kt * 64, &lB[(wid * 32 + i * 8) * 64]);
    }
    __syncthreads();
#pragma unroll
    for (int ks = 0; ks < 2; ++ks) {
      int segrd = ((ks * 4 + lhi) * 8) ^ rxor;
      bf16x8 a[4], b[4];
#pragma unroll
      for (int m = 0; m < 4; ++m)
        a[m] = *(const bf16x8*)&lA[(wr * 64 + m * 16 + l15) * 64 + segrd];
#pragma unroll
      for (int n = 0; n < 4; ++n)
        b[n] = *(const bf16x8*)&lB[(wc * 64 + n * 16 + l15) * 64 + segrd];
#pragma unroll
      for (int m = 0; m < 4; ++m)
#pragma unroll
        for (int n = 0; n < 4; ++n)
          acc[m][n] = __builtin_amdgcn_mfma_f32_16x16x32_bf16(a[m], b[n], acc[m][n], 0, 0, 0);
    }
    __syncthreads();
  }

#pragma unroll
  for (int n = 0; n < 4; ++n) {
    int col = nblk * 128 + wc * 64 + n * 16 + l15;
    float bb = b2[e * DIM_ + col];
#pragma unroll
    for (int m = 0; m < 4; ++m) {
#pragma unroll
      for (int j = 0; j < 4; ++j) {
        int rt = wr * 64 + m * 16 + lhi * 4 + j;
        int gr = mblk * 128 + rt;
        if (gr < cnt)
          ybuf[(size_t)(base + gr) * DIM_ + col] = f2bf(sW[rt] * (acc[m][n][j] + bb));
      }
    }
  }
}

// ---------------- combine: out[t] = ybuf[slot(t,0)] + ybuf[slot(t,1)] ----------------

__global__ void combine(const u16* __restrict__ ybuf, const int* __restrict__ tokrec,
                        const int* __restrict__ counts, float* __restrict__ out) {
  __shared__ int sbase[8];
  int tid = threadIdx.x;
  if (tid == 0) {
    int b = 0;
#pragma unroll
    for (int e = 0; e < 8; ++e) { sbase[e] = b; b += counts[e]; }
  }
  __syncthreads();
  int t = blockIdx.x;
  int r0 = tokrec[t * 2 + 0], r1 = tokrec[t * 2 + 1];
  size_t s0 = (size_t)(sbase[r0 >> 13] + (r0 & 8191)) * DIM_;
  size_t s1 = (size_t)(sbase[r1 >> 13] + (r1 & 8191)) * DIM_;
  int c = tid * 4;
  ushort4 a = *(const ushort4*)(ybuf + s0 + c);
  ushort4 b = *(const ushort4*)(ybuf + s1 + c);
  float4 o;
  o.x = bf2f(a.x) + bf2f(b.x);
  o.y = bf2f(a.y) + bf2f(b.y);
  o.z = bf2f(a.z) + bf2f(b.z);
  o.w = bf2f(a.w) + bf2f(b.w);
  *(float4*)(out + (size_t)t * DIM_ + c) = o;
}

// ---------------- launch ----------------

extern "C" void kernel_launch(void* const* d_in, const int* in_sizes, int n_in,
                              void* d_out, int out_size, void* d_ws, size_t ws_size,
                              hipStream_t stream) {
  const float* x  = (const float*)d_in[0];
  const float* rw = (const float*)d_in[1];
  const float* rb = (const float*)d_in[2];
  const float* W1 = (const float*)d_in[3];
  const float* b1 = (const float*)d_in[4];
  const float* W2 = (const float*)d_in[5];
  const float* b2 = (const float*)d_in[6];
  float* out = (float*)d_out;

  char* ws = (char*)d_ws;
  int*   counts = (int*)ws;                         // 32 B (256 pad)
  int*   btok   = (int*)(ws + 256);                 // 256 KB
  float* bw     = (float*)(ws + 256 + 262144);      // 256 KB
  int*   tokrec = (int*)(ws + 256 + 524288);        // 64 KB
  u16* xb  = (u16*)(ws + (1u << 20));               // 16 MB
  u16* w1t = xb  + (size_t)NTOK * DIM_;             // 64 MB
  u16* w2t = w1t + (size_t)E_ * H2_ * DIM_;         // 32 MB
  u16* hb  = w2t + (size_t)E_ * DIM_ * HID_;        // (16384+128)*2048*2 B
  u16* ybuf = w1t;  // alias: w1t is dead after gemm1; ybuf (33.6 MB) < 64 MB

  hipMemsetAsync(counts, 0, 8 * sizeof(int), stream);

  cvt_x<<<(NTOK * DIM_ / 8 + 255) / 256, 256, 0, stream>>>(x, xb, NTOK * DIM_ / 8);
  tconv<<<dim3(H2_ / 32, DIM_ / 32, E_), 256, 0, stream>>>(W1, w1t, DIM_, H2_);
  tconv<<<dim3(DIM_ / 32, HID_ / 32, E_), 256, 0, stream>>>(W2, w2t, HID_, DIM_);
  router<<<NTOK / 4, 256, 0, stream>>>(x, rw, rb, counts, btok, bw, tokrec);

  gemm1<<<dim3(H2_ / 128, NTOK / 128, E_), 256, 0, stream>>>(xb, w1t, b1, counts, btok, hb);
  gemm2<<<dim3(DIM_ / 128, NTOK / 128, E_), 256, 0, stream>>>(hb, w2t, b2, counts, bw, ybuf);
  combine<<<NTOK, 256, 0, stream>>>(ybuf, tokrec, counts, out);
}

// Round 5
// 403.399 us; speedup vs baseline: 1.5745x; 1.4098x over previous
//
#include <hip/hip_runtime.h>
#include <stdint.h>

typedef unsigned short u16;

#define E_    8
#define DIM_  1024
#define HID_  2048
#define H2_   4096     // 2*HID
#define NTOK  8192     // B*T
#define RTOK  32       // tokens per router block

typedef __attribute__((ext_vector_type(8))) short bf16x8;
typedef __attribute__((ext_vector_type(4))) float f32x4;

__device__ __forceinline__ u16 f2bf(float f) {
  uint32_t u = __builtin_bit_cast(uint32_t, f);
  uint32_t r = (u + 0x7FFFu + ((u >> 16) & 1u)) >> 16;
  return (u16)r;
}
__device__ __forceinline__ float bf2f(u16 u) {
  return __builtin_bit_cast(float, (uint32_t)u << 16);
}

__device__ __forceinline__ void gload16(const void* g, void* l) {
  __builtin_amdgcn_global_load_lds(
      (const __attribute__((address_space(1))) void*)g,
      (__attribute__((address_space(3))) void*)l, 16, 0, 0);
}

// ---------------- conversion kernels ----------------

__global__ void cvt_x(const float* __restrict__ x, u16* __restrict__ xb, int n8) {
  int i = blockIdx.x * blockDim.x + threadIdx.x;
  if (i >= n8) return;
  const float4* p = (const float4*)(x + (size_t)i * 8);
  float4 a = p[0], b = p[1];
  union { u16 u[8]; uint4 v; } r;
  r.u[0] = f2bf(a.x); r.u[1] = f2bf(a.y); r.u[2] = f2bf(a.z); r.u[3] = f2bf(a.w);
  r.u[4] = f2bf(b.x); r.u[5] = f2bf(b.y); r.u[6] = f2bf(b.z); r.u[7] = f2bf(b.w);
  *(uint4*)(xb + (size_t)i * 8) = r.v;
}

// src [e][R][C] fp32 -> dst [e][C][R] bf16 (32x32 tiles)
__global__ void tconv(const float* __restrict__ src, u16* __restrict__ dst, int R, int C) {
  __shared__ float t[32][33];
  int e = blockIdx.z;
  int r0 = blockIdx.y * 32, c0 = blockIdx.x * 32;
  const float* s = src + (size_t)e * R * C;
  u16* d = dst + (size_t)e * R * C;
  int tid = threadIdx.x;
  int rr = tid >> 3, cc = (tid & 7) * 4;
  float4 v = *(const float4*)(s + (size_t)(r0 + rr) * C + c0 + cc);
  t[rr][cc + 0] = v.x; t[rr][cc + 1] = v.y; t[rr][cc + 2] = v.z; t[rr][cc + 3] = v.w;
  __syncthreads();
  ushort4 w;
  w.x = f2bf(t[cc + 0][rr]);
  w.y = f2bf(t[cc + 1][rr]);
  w.z = f2bf(t[cc + 2][rr]);
  w.w = f2bf(t[cc + 3][rr]);
  *(ushort4*)(d + (size_t)(c0 + rr) * R + r0 + cc) = w;
}

// ---------------- router (block-aggregated, low-contention atomics) ----------------

__global__ void router(const float* __restrict__ x, const float* __restrict__ rw,
                       const float* __restrict__ rb, int* __restrict__ counts,
                       int* __restrict__ btok, float* __restrict__ bw,
                       int* __restrict__ tokrec) {
  __shared__ float srw[E_ * DIM_];   // 32 KB
  __shared__ float sb[E_];
  __shared__ int   hcnt[E_], hbase[E_];
  __shared__ int   te[RTOK * 2];
  __shared__ float twt[RTOK * 2];
  __shared__ int   tloc[RTOK * 2];

  int tid = threadIdx.x;
  for (int i = tid; i < E_ * DIM_ / 4; i += 256)
    ((float4*)srw)[i] = ((const float4*)rw)[i];
  if (tid < E_) { sb[tid] = rb[tid]; hcnt[tid] = 0; }
  __syncthreads();

  int wid = tid >> 6, lane = tid & 63;
#pragma unroll
  for (int s = 0; s < RTOK / 4; ++s) {
    int lt = wid * (RTOK / 4) + s;
    int t = blockIdx.x * RTOK + lt;
    const float* xt = x + (size_t)t * DIM_;
    float acc[8] = {0.f, 0.f, 0.f, 0.f, 0.f, 0.f, 0.f, 0.f};
#pragma unroll
    for (int it = 0; it < 4; ++it) {
      int d = it * 256 + lane * 4;
      float4 xv = *(const float4*)(xt + d);
#pragma unroll
      for (int e = 0; e < 8; ++e) {
        float4 rv = *(const float4*)(&srw[e * DIM_ + d]);
        acc[e] += xv.x * rv.x + xv.y * rv.y + xv.z * rv.z + xv.w * rv.w;
      }
    }
#pragma unroll
    for (int e = 0; e < 8; ++e)
#pragma unroll
      for (int off = 32; off; off >>= 1)
        acc[e] += __shfl_xor(acc[e], off, 64);
    if (lane == 0) {
      float v[8];
#pragma unroll
      for (int e = 0; e < 8; ++e) v[e] = acc[e] + sb[e];
      int i0 = 0;
#pragma unroll
      for (int e = 1; e < 8; ++e) if (v[e] > v[i0]) i0 = e;
      int i1 = (i0 == 0) ? 1 : 0;
#pragma unroll
      for (int e = 0; e < 8; ++e) if (e != i0 && v[e] > v[i1]) i1 = e;
      float w0 = 1.f / (1.f + expf(v[i1] - v[i0]));
      float w1 = 1.f - w0;
      int l0 = atomicAdd(&hcnt[i0], 1);   // LDS atomics — fast
      int l1 = atomicAdd(&hcnt[i1], 1);
      te[lt * 2 + 0] = i0; twt[lt * 2 + 0] = w0; tloc[lt * 2 + 0] = l0;
      te[lt * 2 + 1] = i1; twt[lt * 2 + 1] = w1; tloc[lt * 2 + 1] = l1;
    }
  }
  __syncthreads();
  if (tid < E_) hbase[tid] = atomicAdd(&counts[tid], hcnt[tid]);  // 8 global atomics/block
  __syncthreads();
  if (tid < RTOK * 2) {
    int e = te[tid];
    int p = hbase[e] + tloc[tid];
    int t = blockIdx.x * RTOK + (tid >> 1);
    btok[e * NTOK + p] = t;
    bw[e * NTOK + p] = twt[tid];
    tokrec[t * 2 + (tid & 1)] = (e << 13) | p;
  }
}

// ---------------- GEMM1: gathered x @ W1 -> swiglu -> hb ----------------
// block tile: 128 rows x 128 B-cols (= 64 swiglu output cols), BK=64
// LDS tiles XOR-swizzled (T2): physical 16B segment s holds logical segment
// s ^ (row&7); staging pre-swizzles the GLOBAL source (rule #21), LDS dest
// stays linear for global_load_lds; reads apply the same XOR.

__launch_bounds__(256, 2)
__global__ void gemm1(const u16* __restrict__ xb, const u16* __restrict__ w1t,
                      const float* __restrict__ b1, const int* __restrict__ counts,
                      const int* __restrict__ btok, u16* __restrict__ hb) {
  int e = blockIdx.z, mblk = blockIdx.y, nblk = blockIdx.x;
  int cnt = counts[e];
  if (mblk * 128 >= cnt) return;
  int base = 0;
#pragma unroll
  for (int i = 0; i < 8; ++i) base += (i < e) ? counts[i] : 0;

  __shared__ u16 lA[128 * 64];
  __shared__ u16 lB[128 * 64];
  __shared__ int sTok[128];

  int tid = threadIdx.x, wid = tid >> 6, lane = tid & 63;
  if (tid < 128) {
    int gr = mblk * 128 + tid;
    sTok[tid] = (gr < cnt) ? btok[e * NTOK + gr] : btok[e * NTOK];
  }
  __syncthreads();

  f32x4 acc[4][4] = {};
  int wr = wid >> 1, wc = wid & 1;
  int l15 = lane & 15, lhi = lane >> 4;
  const size_t w1e = (size_t)e * H2_ * DIM_;

  int segsw = ((lane & 7) ^ ((lane >> 3) & 7)) * 8;
  const u16* gA[4];
  const u16* gB[4];
#pragma unroll
  for (int i = 0; i < 4; ++i) {
    int r = wid * 32 + i * 8 + (lane >> 3);
    gA[i] = xb + (size_t)sTok[r] * DIM_ + segsw;
    int gcol = nblk * 64 + (r >> 6) * 32 + (r & 31) + ((r >> 5) & 1) * 2048;
    gB[i] = w1t + w1e + (size_t)gcol * DIM_ + segsw;
  }
  int rxor = (l15 & 7) * 8;

  for (int kt = 0; kt < DIM_ / 64; ++kt) {
#pragma unroll
    for (int i = 0; i < 4; ++i)
      gload16(gA[i] + kt * 64, &lA[(wid * 32 + i * 8) * 64]);
#pragma unroll
    for (int i = 0; i < 4; ++i)
      gload16(gB[i] + kt * 64, &lB[(wid * 32 + i * 8) * 64]);
    __syncthreads();
#pragma unroll
    for (int ks = 0; ks < 2; ++ks) {
      int segrd = ((ks * 4 + lhi) * 8) ^ rxor;
      bf16x8 a[4], b[4];
#pragma unroll
      for (int m = 0; m < 4; ++m)
        a[m] = *(const bf16x8*)&lA[(wr * 64 + m * 16 + l15) * 64 + segrd];
#pragma unroll
      for (int n = 0; n < 4; ++n)
        b[n] = *(const bf16x8*)&lB[(wc * 64 + n * 16 + l15) * 64 + segrd];
#pragma unroll
      for (int m = 0; m < 4; ++m)
#pragma unroll
        for (int n = 0; n < 4; ++n)
          acc[m][n] = __builtin_amdgcn_mfma_f32_16x16x32_bf16(a[m], b[n], acc[m][n], 0, 0, 0);
    }
    __syncthreads();
  }

#pragma unroll
  for (int n = 0; n < 2; ++n) {
    int outcol = nblk * 64 + wc * 32 + n * 16 + l15;
    float bb1 = b1[e * H2_ + outcol];
    float bb2 = b1[e * H2_ + outcol + HID_];
#pragma unroll
    for (int m = 0; m < 4; ++m) {
#pragma unroll
      for (int j = 0; j < 4; ++j) {
        int rt = wr * 64 + m * 16 + lhi * 4 + j;
        int gr = mblk * 128 + rt;
        if (gr < cnt) {
          float h1 = acc[m][n][j] + bb1;
          float h2 = acc[m][n + 2][j] + bb2;
          float s = (h1 / (1.f + __expf(-h1))) * h2;
          hb[(size_t)(base + gr) * HID_ + outcol] = f2bf(s);
        }
      }
    }
  }
}

// ---------------- GEMM2: hb @ W2 -> w*(y+b2) stored bf16 to ybuf ----------------

__launch_bounds__(256, 2)
__global__ void gemm2(const u16* __restrict__ hb, const u16* __restrict__ w2t,
                      const float* __restrict__ b2, const int* __restrict__ counts,
                      const float* __restrict__ bw, u16* __restrict__ ybuf) {
  int e = blockIdx.z, mblk = blockIdx.y, nblk = blockIdx.x;
  int cnt = counts[e];
  if (mblk * 128 >= cnt) return;
  int base = 0;
#pragma unroll
  for (int i = 0; i < 8; ++i) base += (i < e) ? counts[i] : 0;

  __shared__ u16 lA[128 * 64];
  __shared__ u16 lB[128 * 64];
  __shared__ float sW[128];

  int tid = threadIdx.x, wid = tid >> 6, lane = tid & 63;
  if (tid < 128) {
    int gr = mblk * 128 + tid;
    sW[tid] = (gr < cnt) ? bw[e * NTOK + gr] : 0.f;
  }
  __syncthreads();

  f32x4 acc[4][4] = {};
  int wr = wid >> 1, wc = wid & 1;
  int l15 = lane & 15, lhi = lane >> 4;

  int segsw = ((lane & 7) ^ ((lane >> 3) & 7)) * 8;
  const u16* gA[4];
  const u16* gB[4];
#pragma unroll
  for (int i = 0; i < 4; ++i) {
    int r = wid * 32 + i * 8 + (lane >> 3);
    gA[i] = hb + (size_t)(base + mblk * 128 + r) * HID_ + segsw;
    gB[i] = w2t + (size_t)e * DIM_ * HID_ + (size_t)(nblk * 128 + r) * HID_ + segsw;
  }
  int rxor = (l15 & 7) * 8;

  for (int kt = 0; kt < HID_ / 64; ++kt) {
#pragma unroll
    for (int i = 0; i < 4; ++i) {
      gload16(gA[i] + kt * 64, &lA[(wid * 32 + i * 8) * 64]);
      gload16(gB[i] + kt * 64, &lB[(wid * 32 + i * 8) * 64]);
    }
    __syncthreads();
#pragma unroll
    for (int ks = 0; ks < 2; ++ks) {
      int segrd = ((ks * 4 + lhi) * 8) ^ rxor;
      bf16x8 a[4], b[4];
#pragma unroll
      for (int m = 0; m < 4; ++m)
        a[m] = *(const bf16x8*)&lA[(wr * 64 + m * 16 + l15) * 64 + segrd];
#pragma unroll
      for (int n = 0; n < 4; ++n)
        b[n] = *(const bf16x8*)&lB[(wc * 64 + n * 16 + l15) * 64 + segrd];
#pragma unroll
      for (int m = 0; m < 4; ++m)
#pragma unroll
        for (int n = 0; n < 4; ++n)
          acc[m][n] = __builtin_amdgcn_mfma_f32_16x16x32_bf16(a[m], b[n], acc[m][n], 0, 0, 0);
    }
    __syncthreads();
  }

#pragma unroll
  for (int n = 0; n < 4; ++n) {
    int col = nblk * 128 + wc * 64 + n * 16 + l15;
    float bb = b2[e * DIM_ + col];
#pragma unroll
    for (int m = 0; m < 4; ++m) {
#pragma unroll
      for (int j = 0; j < 4; ++j) {
        int rt = wr * 64 + m * 16 + lhi * 4 + j;
        int gr = mblk * 128 + rt;
        if (gr < cnt)
          ybuf[(size_t)(base + gr) * DIM_ + col] = f2bf(sW[rt] * (acc[m][n][j] + bb));
      }
    }
  }
}

// ---------------- combine: out[t] = ybuf[slot(t,0)] + ybuf[slot(t,1)] ----------------

__global__ void combine(const u16* __restrict__ ybuf, const int* __restrict__ tokrec,
                        const int* __restrict__ counts, float* __restrict__ out) {
  __shared__ int sbase[8];
  int tid = threadIdx.x;
  if (tid == 0) {
    int b = 0;
#pragma unroll
    for (int e = 0; e < 8; ++e) { sbase[e] = b; b += counts[e]; }
  }
  __syncthreads();
  int t = blockIdx.x;
  int r0 = tokrec[t * 2 + 0], r1 = tokrec[t * 2 + 1];
  size_t s0 = (size_t)(sbase[r0 >> 13] + (r0 & 8191)) * DIM_;
  size_t s1 = (size_t)(sbase[r1 >> 13] + (r1 & 8191)) * DIM_;
  int c = tid * 4;
  ushort4 a = *(const ushort4*)(ybuf + s0 + c);
  ushort4 b = *(const ushort4*)(ybuf + s1 + c);
  float4 o;
  o.x = bf2f(a.x) + bf2f(b.x);
  o.y = bf2f(a.y) + bf2f(b.y);
  o.z = bf2f(a.z) + bf2f(b.z);
  o.w = bf2f(a.w) + bf2f(b.w);
  *(float4*)(out + (size_t)t * DIM_ + c) = o;
}

// ---------------- launch ----------------

extern "C" void kernel_launch(void* const* d_in, const int* in_sizes, int n_in,
                              void* d_out, int out_size, void* d_ws, size_t ws_size,
                              hipStream_t stream) {
  const float* x  = (const float*)d_in[0];
  const float* rw = (const float*)d_in[1];
  const float* rb = (const float*)d_in[2];
  const float* W1 = (const float*)d_in[3];
  const float* b1 = (const float*)d_in[4];
  const float* W2 = (const float*)d_in[5];
  const float* b2 = (const float*)d_in[6];
  float* out = (float*)d_out;

  char* ws = (char*)d_ws;
  int*   counts = (int*)ws;                         // 32 B (256 pad)
  int*   btok   = (int*)(ws + 256);                 // 256 KB
  float* bw     = (float*)(ws + 256 + 262144);      // 256 KB
  int*   tokrec = (int*)(ws + 256 + 524288);        // 64 KB
  u16* xb  = (u16*)(ws + (1u << 20));               // 16 MB
  u16* w1t = xb  + (size_t)NTOK * DIM_;             // 64 MB
  u16* w2t = w1t + (size_t)E_ * H2_ * DIM_;         // 32 MB
  u16* hb  = w2t + (size_t)E_ * DIM_ * HID_;        // (16384+128)*2048*2 B
  u16* ybuf = w1t;  // alias: w1t is dead after gemm1; ybuf (33.6 MB) < 64 MB

  hipMemsetAsync(counts, 0, 8 * sizeof(int), stream);

  cvt_x<<<(NTOK * DIM_ / 8 + 255) / 256, 256, 0, stream>>>(x, xb, NTOK * DIM_ / 8);
  tconv<<<dim3(H2_ / 32, DIM_ / 32, E_), 256, 0, stream>>>(W1, w1t, DIM_, H2_);
  tconv<<<dim3(DIM_ / 32, HID_ / 32, E_), 256, 0, stream>>>(W2, w2t, HID_, DIM_);
  router<<<NTOK / RTOK, 256, 0, stream>>>(x, rw, rb, counts, btok, bw, tokrec);

  gemm1<<<dim3(H2_ / 128, NTOK / 128, E_), 256, 0, stream>>>(xb, w1t, b1, counts, btok, hb);
  gemm2<<<dim3(DIM_ / 128, NTOK / 128, E_), 256, 0, stream>>>(hb, w2t, b2, counts, bw, ybuf);
  combine<<<NTOK, 256, 0, stream>>>(ybuf, tokrec, counts, out);
}